// Round 1
// baseline (4351.946 us; speedup 1.0000x reference)
//
#include <hip/hip_runtime.h>

// ---------------------------------------------------------------------------
// GRACE GCN 2-layer forward:
//   h  = PReLU( Ahat (X W1) + b1 )
//   out= PReLU( Ahat (h W2) + b2 )
// Ahat: symmetric norm with self loops; deg computed from dst array only.
// N=100000, E=1600000, IN=128, HID=128, OUT=64 (sizes derived from in_sizes).
// ---------------------------------------------------------------------------

#define THREADS 256

// deg[i] = 1.0 (self loop contribution)
__global__ void init_deg_kernel(float* __restrict__ deg, int n) {
    int i = blockIdx.x * blockDim.x + threadIdx.x;
    if (i < n) deg[i] = 1.0f;
}

// deg[dst[e]] += 1
__global__ void count_deg_kernel(const int* __restrict__ dst, float* __restrict__ deg, int e) {
    int i = blockIdx.x * blockDim.x + threadIdx.x;
    if (i < e) atomicAdd(&deg[dst[i]], 1.0f);
}

// dinv[i] = rsqrt(deg[i])   (deg >= 1 always, self loops)
__global__ void make_dinv_kernel(float* __restrict__ deg, int n) {
    int i = blockIdx.x * blockDim.x + threadIdx.x;
    if (i < n) deg[i] = rsqrtf(deg[i]);
}

// H[n, OUTC] = X[n,128] @ W[128, OUTC].  W staged fully in LDS.
// Block: 256 threads = ROWS rows x CG col-groups(4 floats each).
template <int OUTC>
__global__ __launch_bounds__(THREADS) void gemm_kernel(const float* __restrict__ X,
                                                       const float* __restrict__ W,
                                                       float* __restrict__ H, int n) {
    constexpr int CG = OUTC / 4;      // col groups per row
    constexpr int ROWS = THREADS / CG;
    __shared__ float Wl[128 * OUTC];
#pragma unroll
    for (int i = threadIdx.x; i < 128 * OUTC; i += THREADS) Wl[i] = W[i];
    __syncthreads();

    int r  = blockIdx.x * ROWS + (int)threadIdx.x / CG;
    int cg = (int)threadIdx.x % CG;
    if (r >= n) return;

    const float* xr = X + (size_t)r * 128;
    float4 acc = make_float4(0.f, 0.f, 0.f, 0.f);
#pragma unroll 4
    for (int k0 = 0; k0 < 128; k0 += 4) {
        float4 xv = *reinterpret_cast<const float4*>(&xr[k0]);
#pragma unroll
        for (int kk = 0; kk < 4; ++kk) {
            float xs = (kk == 0) ? xv.x : (kk == 1) ? xv.y : (kk == 2) ? xv.z : xv.w;
            float4 wv = *reinterpret_cast<const float4*>(&Wl[(k0 + kk) * OUTC + cg * 4]);
            acc.x += xs * wv.x;
            acc.y += xs * wv.y;
            acc.z += xs * wv.z;
            acc.w += xs * wv.w;
        }
    }
    *reinterpret_cast<float4*>(&H[(size_t)r * OUTC + cg * 4]) = acc;
}

// out[i,:] = H[i,:] * dinv[i]^2   (self-loop term; also initializes out)
template <int F>
__global__ __launch_bounds__(THREADS) void self_init_kernel(const float* __restrict__ H,
                                                            const float* __restrict__ dinv,
                                                            float* __restrict__ out, int n) {
    constexpr int FG = F / 4;
    int idx = blockIdx.x * blockDim.x + threadIdx.x;
    if (idx >= n * FG) return;
    int i = idx / FG, f4 = idx % FG;
    float di = dinv[i];
    float w = di * di;
    float4 v = *reinterpret_cast<const float4*>(&H[(size_t)i * F + f4 * 4]);
    v.x *= w; v.y *= w; v.z *= w; v.w *= w;
    *reinterpret_cast<float4*>(&out[(size_t)i * F + f4 * 4]) = v;
}

// out[dst,:] += H[src,:] * dinv[src]*dinv[dst]   per edge (atomic)
template <int F>
__global__ __launch_bounds__(THREADS) void edge_agg_kernel(const float* __restrict__ H,
                                                           const float* __restrict__ dinv,
                                                           const int* __restrict__ src,
                                                           const int* __restrict__ dst,
                                                           float* __restrict__ out, int e) {
    constexpr int TPE = F / 4;  // threads per edge
    int idx = blockIdx.x * blockDim.x + threadIdx.x;
    int eid = idx / TPE;
    int f4  = idx % TPE;
    if (eid >= e) return;
    int s = src[eid];
    int d = dst[eid];
    float nrm = dinv[s] * dinv[d];
    float4 v = *reinterpret_cast<const float4*>(&H[(size_t)s * F + f4 * 4]);
    float* o = &out[(size_t)d * F + f4 * 4];
    atomicAdd(o + 0, v.x * nrm);
    atomicAdd(o + 1, v.y * nrm);
    atomicAdd(o + 2, v.z * nrm);
    atomicAdd(o + 3, v.w * nrm);
}

// buf[i,f] = prelu(buf[i,f] + b[f], a)   in place
template <int F>
__global__ __launch_bounds__(THREADS) void bias_prelu_kernel(float* __restrict__ buf,
                                                             const float* __restrict__ b,
                                                             const float* __restrict__ a_ptr,
                                                             int n) {
    constexpr int FG = F / 4;
    int idx = blockIdx.x * blockDim.x + threadIdx.x;
    if (idx >= n * FG) return;
    int i = idx / FG, f4 = idx % FG;
    float a = *a_ptr;
    float4 v = *reinterpret_cast<float4*>(&buf[(size_t)i * F + f4 * 4]);
    float4 bb = *reinterpret_cast<const float4*>(&b[f4 * 4]);
    v.x += bb.x; v.y += bb.y; v.z += bb.z; v.w += bb.w;
    v.x = v.x >= 0.f ? v.x : a * v.x;
    v.y = v.y >= 0.f ? v.y : a * v.y;
    v.z = v.z >= 0.f ? v.z : a * v.z;
    v.w = v.w >= 0.f ? v.w : a * v.w;
    *reinterpret_cast<float4*>(&buf[(size_t)i * F + f4 * 4]) = v;
}

extern "C" void kernel_launch(void* const* d_in, const int* in_sizes, int n_in,
                              void* d_out, int out_size, void* d_ws, size_t ws_size,
                              hipStream_t stream) {
    const float* x   = (const float*)d_in[0];
    const int*   ei  = (const int*)d_in[1];
    const float* W1  = (const float*)d_in[2];
    const float* b1  = (const float*)d_in[3];
    const float* W2  = (const float*)d_in[4];
    const float* b2  = (const float*)d_in[5];
    const float* a   = (const float*)d_in[6];

    const int IN  = 128;
    const int HID = 128;
    const int OUT = 64;
    const int n = in_sizes[0] / IN;       // 100000
    const int e = in_sizes[1] / 2;        // 1600000
    const int* src = ei;                  // edge_index[0]
    const int* dst = ei + e;              // edge_index[1]

    // workspace layout (floats):
    //   dinv : n
    //   h    : n*128   (layer1 GEMM out; reused as layer2 GEMM out)
    //   agg  : n*128   (layer1 aggregate -> becomes h2 after bias+prelu)
    char* ws = (char*)d_ws;
    size_t off = 0;
    float* dinv = (float*)(ws + off); off += ((size_t)n * 4 + 255) / 256 * 256;
    float* h    = (float*)(ws + off); off += (size_t)n * HID * 4;
    float* agg  = (float*)(ws + off);

    float* out = (float*)d_out;

    int gb;

    // degree -> dinv
    gb = (n + THREADS - 1) / THREADS;
    init_deg_kernel<<<gb, THREADS, 0, stream>>>(dinv, n);
    gb = (e + THREADS - 1) / THREADS;
    count_deg_kernel<<<gb, THREADS, 0, stream>>>(dst, dinv, e);
    gb = (n + THREADS - 1) / THREADS;
    make_dinv_kernel<<<gb, THREADS, 0, stream>>>(dinv, n);

    // ---- layer 1 ----
    {
        constexpr int ROWS = THREADS / (128 / 4);  // 8 rows/block
        gb = (n + ROWS - 1) / ROWS;
        gemm_kernel<128><<<gb, THREADS, 0, stream>>>(x, W1, h, n);
    }
    gb = ((size_t)n * (HID / 4) + THREADS - 1) / THREADS;
    self_init_kernel<128><<<gb, THREADS, 0, stream>>>(h, dinv, agg, n);
    gb = ((size_t)e * (HID / 4) + THREADS - 1) / THREADS;
    edge_agg_kernel<128><<<gb, THREADS, 0, stream>>>(h, dinv, src, dst, agg, e);
    gb = ((size_t)n * (HID / 4) + THREADS - 1) / THREADS;
    bias_prelu_kernel<128><<<gb, THREADS, 0, stream>>>(agg, b1, a, n);
    // agg now holds h2 [n,128]

    // ---- layer 2 ----
    {
        constexpr int ROWS = THREADS / (64 / 4);   // 16 rows/block
        gb = (n + ROWS - 1) / ROWS;
        gemm_kernel<64><<<gb, THREADS, 0, stream>>>(agg, W2, h, n);  // h reused: [n,64]
    }
    gb = ((size_t)n * (OUT / 4) + THREADS - 1) / THREADS;
    self_init_kernel<64><<<gb, THREADS, 0, stream>>>(h, dinv, out, n);
    gb = ((size_t)e * (OUT / 4) + THREADS - 1) / THREADS;
    edge_agg_kernel<64><<<gb, THREADS, 0, stream>>>(h, dinv, src, dst, out, e);
    gb = ((size_t)n * (OUT / 4) + THREADS - 1) / THREADS;
    bias_prelu_kernel<64><<<gb, THREADS, 0, stream>>>(out, b2, a, n);

    (void)ws_size; (void)n_in; (void)out_size;
}

// Round 2
// 558.642 us; speedup vs baseline: 7.7902x; 7.7902x over previous
//
#include <hip/hip_runtime.h>

// ---------------------------------------------------------------------------
// GRACE GCN 2-layer forward, CSR-gather formulation (no float atomics):
//   build CSR by dst (counting sort) once;
//   h1 = X W1;  h2 = PReLU(Ahat h1 + b1);  g = h2 W2;  out = PReLU(Ahat g + b2)
//   Ahat row i: dinv[i]^2 * h[i] + sum_j dinv[src_j]*dinv[i] * h[src_j]
// ---------------------------------------------------------------------------

#define THREADS 256
#define SCAN_CHUNK 1024   // 256 threads x 4 elements

// -------------------- degree / dinv --------------------
__global__ void zero_int_kernel(int* __restrict__ p, int n) {
    int i = blockIdx.x * blockDim.x + threadIdx.x;
    if (i < n) p[i] = 0;
}

__global__ void count_deg_kernel(const int* __restrict__ dst, int* __restrict__ deg, int e) {
    int i = blockIdx.x * blockDim.x + threadIdx.x;
    if (i < e) atomicAdd(&deg[dst[i]], 1);
}

__global__ void make_dinv_kernel(const int* __restrict__ deg, float* __restrict__ dinv, int n) {
    int i = blockIdx.x * blockDim.x + threadIdx.x;
    if (i < n) dinv[i] = rsqrtf((float)(deg[i] + 1));  // +1 self loop
}

// -------------------- exclusive scan (3 phases) --------------------
__global__ void scan_phaseA_kernel(const int* __restrict__ deg, int* __restrict__ bsum, int n) {
    __shared__ int sdata[256];
    int base = blockIdx.x * SCAN_CHUNK;
    int t = threadIdx.x;
    int s = 0;
#pragma unroll
    for (int k = 0; k < 4; ++k) {
        int idx = base + t * 4 + k;
        if (idx < n) s += deg[idx];
    }
    sdata[t] = s;
    __syncthreads();
    for (int d = 128; d > 0; d >>= 1) {
        if (t < d) sdata[t] += sdata[t + d];
        __syncthreads();
    }
    if (t == 0) bsum[blockIdx.x] = sdata[0];
}

__global__ void scan_phaseB_kernel(int* __restrict__ bsum, int nb) {
    __shared__ int sdata[256];
    __shared__ int carry;
    int t = threadIdx.x;
    if (t == 0) carry = 0;
    __syncthreads();
    for (int base = 0; base < nb; base += 256) {
        int idx = base + t;
        int v = (idx < nb) ? bsum[idx] : 0;
        sdata[t] = v;
        __syncthreads();
        for (int d = 1; d < 256; d <<= 1) {
            int u = (t >= d) ? sdata[t - d] : 0;
            __syncthreads();
            sdata[t] += u;
            __syncthreads();
        }
        int excl = sdata[t] - v + carry;
        if (idx < nb) bsum[idx] = excl;
        int tot = sdata[255];
        __syncthreads();
        if (t == 0) carry += tot;
        __syncthreads();
    }
}

__global__ void scan_phaseC_kernel(const int* __restrict__ deg, const int* __restrict__ bsum,
                                   int* __restrict__ off, int* __restrict__ cursor, int n) {
    __shared__ int sdata[256];
    int base = blockIdx.x * SCAN_CHUNK;
    int t = threadIdx.x;
    int v[4];
    int s = 0;
#pragma unroll
    for (int k = 0; k < 4; ++k) {
        int idx = base + t * 4 + k;
        v[k] = (idx < n) ? deg[idx] : 0;
        s += v[k];
    }
    sdata[t] = s;
    __syncthreads();
    for (int d = 1; d < 256; d <<= 1) {
        int u = (t >= d) ? sdata[t - d] : 0;
        __syncthreads();
        sdata[t] += u;
        __syncthreads();
    }
    int run = bsum[blockIdx.x] + sdata[t] - s;  // exclusive base
#pragma unroll
    for (int k = 0; k < 4; ++k) {
        int idx = base + t * 4 + k;
        if (idx < n) {
            off[idx] = run;
            cursor[idx] = run;
            run += v[k];
            if (idx == n - 1) off[n] = run;
        }
    }
}

// -------------------- edge scatter (counting sort by dst) --------------------
__global__ void scatter_edges_kernel(const int* __restrict__ src, const int* __restrict__ dst,
                                     int* __restrict__ cursor, int* __restrict__ es, int e) {
    int i = blockIdx.x * blockDim.x + threadIdx.x;
    if (i < e) {
        int d = dst[i];
        int pos = atomicAdd(&cursor[d], 1);
        es[pos] = src[i];
    }
}

// -------------------- dense GEMM: H = X[n,128] @ W[128,OUTC] --------------------
template <int OUTC>
__global__ __launch_bounds__(THREADS) void gemm_kernel(const float* __restrict__ X,
                                                       const float* __restrict__ W,
                                                       float* __restrict__ H, int n) {
    constexpr int CG = OUTC / 4;
    constexpr int ROWS = THREADS / CG;
    __shared__ float Wl[128 * OUTC];
#pragma unroll
    for (int i = threadIdx.x; i < 128 * OUTC; i += THREADS) Wl[i] = W[i];
    __syncthreads();

    int r  = blockIdx.x * ROWS + (int)threadIdx.x / CG;
    int cg = (int)threadIdx.x % CG;
    if (r >= n) return;

    const float* xr = X + (size_t)r * 128;
    float4 acc = make_float4(0.f, 0.f, 0.f, 0.f);
#pragma unroll 4
    for (int k0 = 0; k0 < 128; k0 += 4) {
        float4 xv = *reinterpret_cast<const float4*>(&xr[k0]);
#pragma unroll
        for (int kk = 0; kk < 4; ++kk) {
            float xs = (kk == 0) ? xv.x : (kk == 1) ? xv.y : (kk == 2) ? xv.z : xv.w;
            float4 wv = *reinterpret_cast<const float4*>(&Wl[(k0 + kk) * OUTC + cg * 4]);
            acc.x += xs * wv.x;
            acc.y += xs * wv.y;
            acc.z += xs * wv.z;
            acc.w += xs * wv.w;
        }
    }
    *reinterpret_cast<float4*>(&H[(size_t)r * OUTC + cg * 4]) = acc;
}

// -------------------- CSR aggregate + bias + PReLU (fused) --------------------
// out[i,:] = prelu( dinv[i]^2*H[i,:] + sum_j dinv[es[j]]*dinv[i]*H[es[j],:] + b, a )
template <int F>
__global__ __launch_bounds__(THREADS) void agg_kernel(const float* __restrict__ H,
                                                      const float* __restrict__ dinv,
                                                      const int* __restrict__ off,
                                                      const int* __restrict__ es,
                                                      const float* __restrict__ bias,
                                                      const float* __restrict__ a_ptr,
                                                      float* __restrict__ out, int n) {
    constexpr int TPN = F / 4;                 // threads per node (float4 each)
    int node = blockIdx.x * (THREADS / TPN) + (int)threadIdx.x / TPN;
    int f4   = (int)threadIdx.x % TPN;
    if (node >= n) return;

    float di = dinv[node];
    float4 acc = *reinterpret_cast<const float4*>(H + (size_t)node * F + f4 * 4);
    float w0 = di * di;
    acc.x *= w0; acc.y *= w0; acc.z *= w0; acc.w *= w0;

    int j1 = off[node + 1];
    for (int j = off[node]; j < j1; ++j) {
        int s = es[j];
        float w = dinv[s] * di;
        float4 v = *reinterpret_cast<const float4*>(H + (size_t)s * F + f4 * 4);
        acc.x += v.x * w;
        acc.y += v.y * w;
        acc.z += v.z * w;
        acc.w += v.w * w;
    }

    float a = *a_ptr;
    float4 bb = *reinterpret_cast<const float4*>(bias + f4 * 4);
    acc.x += bb.x; acc.y += bb.y; acc.z += bb.z; acc.w += bb.w;
    acc.x = acc.x >= 0.f ? acc.x : a * acc.x;
    acc.y = acc.y >= 0.f ? acc.y : a * acc.y;
    acc.z = acc.z >= 0.f ? acc.z : a * acc.z;
    acc.w = acc.w >= 0.f ? acc.w : a * acc.w;
    *reinterpret_cast<float4*>(out + (size_t)node * F + f4 * 4) = acc;
}

extern "C" void kernel_launch(void* const* d_in, const int* in_sizes, int n_in,
                              void* d_out, int out_size, void* d_ws, size_t ws_size,
                              hipStream_t stream) {
    const float* x   = (const float*)d_in[0];
    const int*   ei  = (const int*)d_in[1];
    const float* W1  = (const float*)d_in[2];
    const float* b1  = (const float*)d_in[3];
    const float* W2  = (const float*)d_in[4];
    const float* b2  = (const float*)d_in[5];
    const float* a   = (const float*)d_in[6];

    const int IN  = 128;
    const int HID = 128;
    const int OUT = 64;
    const int n = in_sizes[0] / IN;       // 100000
    const int e = in_sizes[1] / 2;        // 1600000
    const int* src = ei;
    const int* dst = ei + e;

    auto align = [](size_t v) { return (v + 255) / 256 * 256; };
    char* ws = (char*)d_ws;
    size_t o = 0;
    int*   deg    = (int*)(ws + o);   o += align((size_t)n * 4);
    float* dinv   = (float*)(ws + o); o += align((size_t)n * 4);
    int*   off    = (int*)(ws + o);   o += align(((size_t)n + 1) * 4);
    int*   cursor = (int*)(ws + o);   o += align((size_t)n * 4);
    int*   bsum   = (int*)(ws + o);   o += align((size_t)4096 * 4);
    int*   es     = (int*)(ws + o);   o += align((size_t)e * 4);
    float* h      = (float*)(ws + o); o += align((size_t)n * HID * 4);
    float* h2     = (float*)(ws + o); o += align((size_t)n * HID * 4);
    float* g      = h;                 // reuse h for layer-2 GEMM output [n,64]

    float* out = (float*)d_out;

    int gbN = (n + THREADS - 1) / THREADS;
    int gbE = (e + THREADS - 1) / THREADS;
    int nb  = (n + SCAN_CHUNK - 1) / SCAN_CHUNK;

    // ---- CSR build + dinv ----
    zero_int_kernel<<<gbN, THREADS, 0, stream>>>(deg, n);
    count_deg_kernel<<<gbE, THREADS, 0, stream>>>(dst, deg, e);
    make_dinv_kernel<<<gbN, THREADS, 0, stream>>>(deg, dinv, n);
    scan_phaseA_kernel<<<nb, THREADS, 0, stream>>>(deg, bsum, n);
    scan_phaseB_kernel<<<1, THREADS, 0, stream>>>(bsum, nb);
    scan_phaseC_kernel<<<nb, THREADS, 0, stream>>>(deg, bsum, off, cursor, n);
    scatter_edges_kernel<<<gbE, THREADS, 0, stream>>>(src, dst, cursor, es, e);

    // ---- layer 1 ----
    {
        constexpr int ROWS = THREADS / (128 / 4);  // 8 rows/block
        int gb = (n + ROWS - 1) / ROWS;
        gemm_kernel<128><<<gb, THREADS, 0, stream>>>(x, W1, h, n);
    }
    {
        constexpr int NPB = THREADS / (128 / 4);   // 8 nodes/block
        int gb = (n + NPB - 1) / NPB;
        agg_kernel<128><<<gb, THREADS, 0, stream>>>(h, dinv, off, es, b1, a, h2, n);
    }

    // ---- layer 2 ----
    {
        constexpr int ROWS = THREADS / (64 / 4);   // 16 rows/block
        int gb = (n + ROWS - 1) / ROWS;
        gemm_kernel<64><<<gb, THREADS, 0, stream>>>(h2, W2, g, n);
    }
    {
        constexpr int NPB = THREADS / (64 / 4);    // 16 nodes/block
        int gb = (n + NPB - 1) / NPB;
        agg_kernel<64><<<gb, THREADS, 0, stream>>>(g, dinv, off, es, b2, a, out, n);
    }

    (void)ws_size; (void)n_in; (void)out_size;
}

// Round 3
// 530.354 us; speedup vs baseline: 8.2057x; 1.0533x over previous
//
#include <hip/hip_runtime.h>

// ---------------------------------------------------------------------------
// GRACE GCN 2-layer forward, CSR-gather formulation (no float atomics):
//   build CSR by dst (counting sort) once;
//   h1 = X W1;  h2 = PReLU(Ahat h1 + b1);  g = h2 W2;  out = PReLU(Ahat g + b2)
//   Ahat row i: dinv[i]^2 * h[i] + sum_j dinv[src_j]*dinv[i] * h[src_j]
// GEMM: register-blocked 8 rows x 4 cols per thread -> 128 FMA per 4 LDS reads
// (previous version was LDS-issue-bound: 16 FMA per 4 ds_read_b128, VALUBusy 25%).
// ---------------------------------------------------------------------------

#define THREADS 256
#define SCAN_CHUNK 1024   // 256 threads x 4 elements

// -------------------- degree / dinv --------------------
__global__ void zero_int_kernel(int* __restrict__ p, int n) {
    int i = blockIdx.x * blockDim.x + threadIdx.x;
    if (i < n) p[i] = 0;
}

__global__ void count_deg_kernel(const int* __restrict__ dst, int* __restrict__ deg, int e) {
    int i = blockIdx.x * blockDim.x + threadIdx.x;
    if (i < e) atomicAdd(&deg[dst[i]], 1);
}

__global__ void make_dinv_kernel(const int* __restrict__ deg, float* __restrict__ dinv, int n) {
    int i = blockIdx.x * blockDim.x + threadIdx.x;
    if (i < n) dinv[i] = rsqrtf((float)(deg[i] + 1));  // +1 self loop
}

// -------------------- exclusive scan (3 phases) --------------------
__global__ void scan_phaseA_kernel(const int* __restrict__ deg, int* __restrict__ bsum, int n) {
    __shared__ int sdata[256];
    int base = blockIdx.x * SCAN_CHUNK;
    int t = threadIdx.x;
    int s = 0;
#pragma unroll
    for (int k = 0; k < 4; ++k) {
        int idx = base + t * 4 + k;
        if (idx < n) s += deg[idx];
    }
    sdata[t] = s;
    __syncthreads();
    for (int d = 128; d > 0; d >>= 1) {
        if (t < d) sdata[t] += sdata[t + d];
        __syncthreads();
    }
    if (t == 0) bsum[blockIdx.x] = sdata[0];
}

__global__ void scan_phaseB_kernel(int* __restrict__ bsum, int nb) {
    __shared__ int sdata[256];
    __shared__ int carry;
    int t = threadIdx.x;
    if (t == 0) carry = 0;
    __syncthreads();
    for (int base = 0; base < nb; base += 256) {
        int idx = base + t;
        int v = (idx < nb) ? bsum[idx] : 0;
        sdata[t] = v;
        __syncthreads();
        for (int d = 1; d < 256; d <<= 1) {
            int u = (t >= d) ? sdata[t - d] : 0;
            __syncthreads();
            sdata[t] += u;
            __syncthreads();
        }
        int excl = sdata[t] - v + carry;
        if (idx < nb) bsum[idx] = excl;
        int tot = sdata[255];
        __syncthreads();
        if (t == 0) carry += tot;
        __syncthreads();
    }
}

__global__ void scan_phaseC_kernel(const int* __restrict__ deg, const int* __restrict__ bsum,
                                   int* __restrict__ off, int* __restrict__ cursor, int n) {
    __shared__ int sdata[256];
    int base = blockIdx.x * SCAN_CHUNK;
    int t = threadIdx.x;
    int v[4];
    int s = 0;
#pragma unroll
    for (int k = 0; k < 4; ++k) {
        int idx = base + t * 4 + k;
        v[k] = (idx < n) ? deg[idx] : 0;
        s += v[k];
    }
    sdata[t] = s;
    __syncthreads();
    for (int d = 1; d < 256; d <<= 1) {
        int u = (t >= d) ? sdata[t - d] : 0;
        __syncthreads();
        sdata[t] += u;
        __syncthreads();
    }
    int run = bsum[blockIdx.x] + sdata[t] - s;  // exclusive base
#pragma unroll
    for (int k = 0; k < 4; ++k) {
        int idx = base + t * 4 + k;
        if (idx < n) {
            off[idx] = run;
            cursor[idx] = run;
            run += v[k];
            if (idx == n - 1) off[n] = run;
        }
    }
}

// -------------------- edge scatter (counting sort by dst) --------------------
__global__ void scatter_edges_kernel(const int* __restrict__ src, const int* __restrict__ dst,
                                     int* __restrict__ cursor, int* __restrict__ es, int e) {
    int i = blockIdx.x * blockDim.x + threadIdx.x;
    if (i < e) {
        int d = dst[i];
        int pos = atomicAdd(&cursor[d], 1);
        es[pos] = src[i];
    }
}

// -------------------- dense GEMM: H = X[n,128] @ W[128,OUTC] --------------------
// Register-blocked: each thread computes R=8 rows x 4 cols. Per k0-step:
// 4 ds_read_b128 (W frag, reused over 8 rows) + 8 global b128 (X, lane-broadcast)
// + 128 FMAs -> VALU-bound.
template <int OUTC>
__global__ __launch_bounds__(THREADS) void gemm_kernel(const float* __restrict__ X,
                                                       const float* __restrict__ W,
                                                       float* __restrict__ H, int n) {
    constexpr int CG = OUTC / 4;          // col-groups (4 floats each)
    constexpr int RG = THREADS / CG;      // row-groups per block
    constexpr int R  = 8;                 // rows per thread
    constexpr int ROWS = RG * R;          // rows per block
    __shared__ float Wl[128 * OUTC];
    {
        const float4* Wv = reinterpret_cast<const float4*>(W);
        float4* Wlv = reinterpret_cast<float4*>(Wl);
        for (int i = threadIdx.x; i < 128 * OUTC / 4; i += THREADS) Wlv[i] = Wv[i];
    }
    __syncthreads();

    int cg = (int)threadIdx.x % CG;
    int rg = (int)threadIdx.x / CG;
    int rbase = blockIdx.x * ROWS + rg * R;

    int rr[R];
#pragma unroll
    for (int r = 0; r < R; ++r) {
        int q = rbase + r;
        rr[r] = q < n ? q : (n - 1);   // clamp: loads stay in-bounds, store guarded
    }

    float4 acc[R];
#pragma unroll
    for (int r = 0; r < R; ++r) acc[r] = make_float4(0.f, 0.f, 0.f, 0.f);

#pragma unroll 4
    for (int k0 = 0; k0 < 128; k0 += 4) {
        float4 w0 = *reinterpret_cast<const float4*>(&Wl[(k0 + 0) * OUTC + cg * 4]);
        float4 w1 = *reinterpret_cast<const float4*>(&Wl[(k0 + 1) * OUTC + cg * 4]);
        float4 w2 = *reinterpret_cast<const float4*>(&Wl[(k0 + 2) * OUTC + cg * 4]);
        float4 w3 = *reinterpret_cast<const float4*>(&Wl[(k0 + 3) * OUTC + cg * 4]);
#pragma unroll
        for (int r = 0; r < R; ++r) {
            float4 xv = *reinterpret_cast<const float4*>(&X[(size_t)rr[r] * 128 + k0]);
            acc[r].x += xv.x * w0.x + xv.y * w1.x + xv.z * w2.x + xv.w * w3.x;
            acc[r].y += xv.x * w0.y + xv.y * w1.y + xv.z * w2.y + xv.w * w3.y;
            acc[r].z += xv.x * w0.z + xv.y * w1.z + xv.z * w2.z + xv.w * w3.z;
            acc[r].w += xv.x * w0.w + xv.y * w1.w + xv.z * w2.w + xv.w * w3.w;
        }
    }

#pragma unroll
    for (int r = 0; r < R; ++r) {
        int q = rbase + r;
        if (q < n) *reinterpret_cast<float4*>(&H[(size_t)q * OUTC + cg * 4]) = acc[r];
    }
}

// -------------------- CSR aggregate + bias + PReLU (fused) --------------------
// out[i,:] = prelu( dinv[i]^2*H[i,:] + sum_j dinv[es[j]]*dinv[i]*H[es[j],:] + b, a )
template <int F>
__global__ __launch_bounds__(THREADS) void agg_kernel(const float* __restrict__ H,
                                                      const float* __restrict__ dinv,
                                                      const int* __restrict__ off,
                                                      const int* __restrict__ es,
                                                      const float* __restrict__ bias,
                                                      const float* __restrict__ a_ptr,
                                                      float* __restrict__ out, int n) {
    constexpr int TPN = F / 4;                 // threads per node (float4 each)
    int node = blockIdx.x * (THREADS / TPN) + (int)threadIdx.x / TPN;
    int f4   = (int)threadIdx.x % TPN;
    if (node >= n) return;

    float di = dinv[node];
    float4 acc = *reinterpret_cast<const float4*>(H + (size_t)node * F + f4 * 4);
    float w0 = di * di;
    acc.x *= w0; acc.y *= w0; acc.z *= w0; acc.w *= w0;

    int j1 = off[node + 1];
    for (int j = off[node]; j < j1; ++j) {
        int s = es[j];
        float w = dinv[s] * di;
        float4 v = *reinterpret_cast<const float4*>(H + (size_t)s * F + f4 * 4);
        acc.x += v.x * w;
        acc.y += v.y * w;
        acc.z += v.z * w;
        acc.w += v.w * w;
    }

    float a = *a_ptr;
    float4 bb = *reinterpret_cast<const float4*>(bias + f4 * 4);
    acc.x += bb.x; acc.y += bb.y; acc.z += bb.z; acc.w += bb.w;
    acc.x = acc.x >= 0.f ? acc.x : a * acc.x;
    acc.y = acc.y >= 0.f ? acc.y : a * acc.y;
    acc.z = acc.z >= 0.f ? acc.z : a * acc.z;
    acc.w = acc.w >= 0.f ? acc.w : a * acc.w;
    *reinterpret_cast<float4*>(out + (size_t)node * F + f4 * 4) = acc;
}

extern "C" void kernel_launch(void* const* d_in, const int* in_sizes, int n_in,
                              void* d_out, int out_size, void* d_ws, size_t ws_size,
                              hipStream_t stream) {
    const float* x   = (const float*)d_in[0];
    const int*   ei  = (const int*)d_in[1];
    const float* W1  = (const float*)d_in[2];
    const float* b1  = (const float*)d_in[3];
    const float* W2  = (const float*)d_in[4];
    const float* b2  = (const float*)d_in[5];
    const float* a   = (const float*)d_in[6];

    const int IN  = 128;
    const int HID = 128;
    const int OUT = 64;
    const int n = in_sizes[0] / IN;       // 100000
    const int e = in_sizes[1] / 2;        // 1600000
    const int* src = ei;
    const int* dst = ei + e;

    auto align = [](size_t v) { return (v + 255) / 256 * 256; };
    char* ws = (char*)d_ws;
    size_t o = 0;
    int*   deg    = (int*)(ws + o);   o += align((size_t)n * 4);
    float* dinv   = (float*)(ws + o); o += align((size_t)n * 4);
    int*   off    = (int*)(ws + o);   o += align(((size_t)n + 1) * 4);
    int*   cursor = (int*)(ws + o);   o += align((size_t)n * 4);
    int*   bsum   = (int*)(ws + o);   o += align((size_t)4096 * 4);
    int*   es     = (int*)(ws + o);   o += align((size_t)e * 4);
    float* h      = (float*)(ws + o); o += align((size_t)n * HID * 4);
    float* h2     = (float*)(ws + o); o += align((size_t)n * HID * 4);
    float* g      = h;                 // reuse h for layer-2 GEMM output [n,64]

    float* out = (float*)d_out;

    int gbN = (n + THREADS - 1) / THREADS;
    int gbE = (e + THREADS - 1) / THREADS;
    int nb  = (n + SCAN_CHUNK - 1) / SCAN_CHUNK;

    // ---- CSR build + dinv ----
    zero_int_kernel<<<gbN, THREADS, 0, stream>>>(deg, n);
    count_deg_kernel<<<gbE, THREADS, 0, stream>>>(dst, deg, e);
    make_dinv_kernel<<<gbN, THREADS, 0, stream>>>(deg, dinv, n);
    scan_phaseA_kernel<<<nb, THREADS, 0, stream>>>(deg, bsum, n);
    scan_phaseB_kernel<<<1, THREADS, 0, stream>>>(bsum, nb);
    scan_phaseC_kernel<<<nb, THREADS, 0, stream>>>(deg, bsum, off, cursor, n);
    scatter_edges_kernel<<<gbE, THREADS, 0, stream>>>(src, dst, cursor, es, e);

    // ---- layer 1 ----
    {
        constexpr int ROWS = (THREADS / (128 / 4)) * 8;  // 64 rows/block
        int gb = (n + ROWS - 1) / ROWS;
        gemm_kernel<128><<<gb, THREADS, 0, stream>>>(x, W1, h, n);
    }
    {
        constexpr int NPB = THREADS / (128 / 4);   // 8 nodes/block
        int gb = (n + NPB - 1) / NPB;
        agg_kernel<128><<<gb, THREADS, 0, stream>>>(h, dinv, off, es, b1, a, h2, n);
    }

    // ---- layer 2 ----
    {
        constexpr int ROWS = (THREADS / (64 / 4)) * 8;   // 128 rows/block
        int gb = (n + ROWS - 1) / ROWS;
        gemm_kernel<64><<<gb, THREADS, 0, stream>>>(h2, W2, g, n);
    }
    {
        constexpr int NPB = THREADS / (64 / 4);    // 16 nodes/block
        int gb = (n + NPB - 1) / NPB;
        agg_kernel<64><<<gb, THREADS, 0, stream>>>(g, dinv, off, es, b2, a, out, n);
    }

    (void)ws_size; (void)n_in; (void)out_size;
}

// Round 4
// 415.745 us; speedup vs baseline: 10.4678x; 1.2757x over previous
//
#include <hip/hip_runtime.h>

// ---------------------------------------------------------------------------
// GRACE GCN 2-layer forward, CSR-gather formulation, bf16 intermediates:
//   h1' = (X W1) * dinv      (bf16, pre-scaled by source dinv)
//   h2  = prelu(dinv_d*(h1'_d + sum_j h1'_es[j]) + b1)    (bf16)
//   g'  = (h2 W2) * dinv     (bf16)
//   out = prelu(dinv_d*(g'_d + sum_j g'_es[j]) + b2)      (f32)
// Pre-scaling by dinv at GEMM output removes the per-edge dinv[src] gather +
// multiply from the agg inner loop; bf16 halves gather bytes (the agg kernels
// were gather-BW-bound: 415 MB FETCH, 3.65 TB/s effective, VALUBusy 13%).
// ---------------------------------------------------------------------------

#define THREADS 256
#define SCAN_CHUNK 1024   // 256 threads x 4 elements

typedef unsigned short bf16_t;

__device__ __forceinline__ float bflo(unsigned int w) {
    union { unsigned int u; float f; } v; v.u = w << 16; return v.f;
}
__device__ __forceinline__ float bfhi(unsigned int w) {
    union { unsigned int u; float f; } v; v.u = w & 0xffff0000u; return v.f;
}
__device__ __forceinline__ unsigned int f2bf(float f) {  // RNE
    union { float f; unsigned int u; } v; v.f = f;
    return (v.u + 0x7fffu + ((v.u >> 16) & 1u)) >> 16;
}

// -------------------- degree / dinv --------------------
__global__ void zero_int_kernel(int* __restrict__ p, int n) {
    int i = blockIdx.x * blockDim.x + threadIdx.x;
    if (i < n) p[i] = 0;
}

__global__ void count_deg_kernel(const int* __restrict__ dst, int* __restrict__ deg, int e) {
    int i = blockIdx.x * blockDim.x + threadIdx.x;
    if (i < e) atomicAdd(&deg[dst[i]], 1);
}

__global__ void make_dinv_kernel(const int* __restrict__ deg, float* __restrict__ dinv, int n) {
    int i = blockIdx.x * blockDim.x + threadIdx.x;
    if (i < n) dinv[i] = rsqrtf((float)(deg[i] + 1));  // +1 self loop
}

// -------------------- exclusive scan (3 phases) --------------------
__global__ void scan_phaseA_kernel(const int* __restrict__ deg, int* __restrict__ bsum, int n) {
    __shared__ int sdata[256];
    int base = blockIdx.x * SCAN_CHUNK;
    int t = threadIdx.x;
    int s = 0;
#pragma unroll
    for (int k = 0; k < 4; ++k) {
        int idx = base + t * 4 + k;
        if (idx < n) s += deg[idx];
    }
    sdata[t] = s;
    __syncthreads();
    for (int d = 128; d > 0; d >>= 1) {
        if (t < d) sdata[t] += sdata[t + d];
        __syncthreads();
    }
    if (t == 0) bsum[blockIdx.x] = sdata[0];
}

__global__ void scan_phaseB_kernel(int* __restrict__ bsum, int nb) {
    __shared__ int sdata[256];
    __shared__ int carry;
    int t = threadIdx.x;
    if (t == 0) carry = 0;
    __syncthreads();
    for (int base = 0; base < nb; base += 256) {
        int idx = base + t;
        int v = (idx < nb) ? bsum[idx] : 0;
        sdata[t] = v;
        __syncthreads();
        for (int d = 1; d < 256; d <<= 1) {
            int u = (t >= d) ? sdata[t - d] : 0;
            __syncthreads();
            sdata[t] += u;
            __syncthreads();
        }
        int excl = sdata[t] - v + carry;
        if (idx < nb) bsum[idx] = excl;
        int tot = sdata[255];
        __syncthreads();
        if (t == 0) carry += tot;
        __syncthreads();
    }
}

__global__ void scan_phaseC_kernel(const int* __restrict__ deg, const int* __restrict__ bsum,
                                   int* __restrict__ off, int* __restrict__ cursor, int n) {
    __shared__ int sdata[256];
    int base = blockIdx.x * SCAN_CHUNK;
    int t = threadIdx.x;
    int v[4];
    int s = 0;
#pragma unroll
    for (int k = 0; k < 4; ++k) {
        int idx = base + t * 4 + k;
        v[k] = (idx < n) ? deg[idx] : 0;
        s += v[k];
    }
    sdata[t] = s;
    __syncthreads();
    for (int d = 1; d < 256; d <<= 1) {
        int u = (t >= d) ? sdata[t - d] : 0;
        __syncthreads();
        sdata[t] += u;
        __syncthreads();
    }
    int run = bsum[blockIdx.x] + sdata[t] - s;  // exclusive base
#pragma unroll
    for (int k = 0; k < 4; ++k) {
        int idx = base + t * 4 + k;
        if (idx < n) {
            off[idx] = run;
            cursor[idx] = run;
            run += v[k];
            if (idx == n - 1) off[n] = run;
        }
    }
}

// -------------------- edge scatter (counting sort by dst) --------------------
__global__ void scatter_edges_kernel(const int* __restrict__ src, const int* __restrict__ dst,
                                     int* __restrict__ cursor, int* __restrict__ es, int e) {
    int i = blockIdx.x * blockDim.x + threadIdx.x;
    if (i < e) {
        int d = dst[i];
        int pos = atomicAdd(&cursor[d], 1);
        es[pos] = src[i];
    }
}

// -------------------- dense GEMM: H = (X[n,128] @ W[128,OUTC]) * rowscale ----
// Register-blocked 8 rows x 4 cols/thread; W staged in LDS (f32); output bf16.
template <int OUTC, bool XBF>
__global__ __launch_bounds__(THREADS) void gemm_kernel(const void* __restrict__ Xv,
                                                       const float* __restrict__ W,
                                                       const float* __restrict__ rowscale,
                                                       bf16_t* __restrict__ H, int n) {
    constexpr int CG = OUTC / 4;          // col-groups (4 floats each)
    constexpr int RG = THREADS / CG;      // row-groups per block
    constexpr int R  = 8;                 // rows per thread
    constexpr int ROWS = RG * R;          // rows per block
    __shared__ float Wl[128 * OUTC];
    {
        const float4* Wv = reinterpret_cast<const float4*>(W);
        float4* Wlv = reinterpret_cast<float4*>(Wl);
        for (int i = threadIdx.x; i < 128 * OUTC / 4; i += THREADS) Wlv[i] = Wv[i];
    }
    __syncthreads();

    int cg = (int)threadIdx.x % CG;
    int rg = (int)threadIdx.x / CG;
    int rbase = blockIdx.x * ROWS + rg * R;

    int rr[R];
#pragma unroll
    for (int r = 0; r < R; ++r) {
        int q = rbase + r;
        rr[r] = q < n ? q : (n - 1);   // clamp: loads in-bounds, store guarded
    }

    float4 acc[R];
#pragma unroll
    for (int r = 0; r < R; ++r) acc[r] = make_float4(0.f, 0.f, 0.f, 0.f);

#pragma unroll 4
    for (int k0 = 0; k0 < 128; k0 += 4) {
        float4 w0 = *reinterpret_cast<const float4*>(&Wl[(k0 + 0) * OUTC + cg * 4]);
        float4 w1 = *reinterpret_cast<const float4*>(&Wl[(k0 + 1) * OUTC + cg * 4]);
        float4 w2 = *reinterpret_cast<const float4*>(&Wl[(k0 + 2) * OUTC + cg * 4]);
        float4 w3 = *reinterpret_cast<const float4*>(&Wl[(k0 + 3) * OUTC + cg * 4]);
#pragma unroll
        for (int r = 0; r < R; ++r) {
            float xs0, xs1, xs2, xs3;
            if constexpr (XBF) {
                const bf16_t* Xb = (const bf16_t*)Xv;
                uint2 xu = *reinterpret_cast<const uint2*>(Xb + (size_t)rr[r] * 128 + k0);
                xs0 = bflo(xu.x); xs1 = bfhi(xu.x); xs2 = bflo(xu.y); xs3 = bfhi(xu.y);
            } else {
                float4 xv = *reinterpret_cast<const float4*>((const float*)Xv + (size_t)rr[r] * 128 + k0);
                xs0 = xv.x; xs1 = xv.y; xs2 = xv.z; xs3 = xv.w;
            }
            acc[r].x += xs0 * w0.x + xs1 * w1.x + xs2 * w2.x + xs3 * w3.x;
            acc[r].y += xs0 * w0.y + xs1 * w1.y + xs2 * w2.y + xs3 * w3.y;
            acc[r].z += xs0 * w0.z + xs1 * w1.z + xs2 * w2.z + xs3 * w3.z;
            acc[r].w += xs0 * w0.w + xs1 * w1.w + xs2 * w2.w + xs3 * w3.w;
        }
    }

#pragma unroll
    for (int r = 0; r < R; ++r) {
        int q = rbase + r;
        if (q < n) {
            float s = rowscale[q];
            ushort4 o;
            o.x = (unsigned short)f2bf(acc[r].x * s);
            o.y = (unsigned short)f2bf(acc[r].y * s);
            o.z = (unsigned short)f2bf(acc[r].z * s);
            o.w = (unsigned short)f2bf(acc[r].w * s);
            *reinterpret_cast<ushort4*>(&H[(size_t)q * OUTC + cg * 4]) = o;
        }
    }
}

// -------------------- CSR aggregate + bias + PReLU (fused, bf16 gather) -----
// out[i,:] = prelu( dinv[i]*(H'[i,:] + sum_j H'[es[j],:]) + b, a )
template <int F, bool OUTBF>
__global__ __launch_bounds__(THREADS) void agg_kernel(const bf16_t* __restrict__ H,
                                                      const float* __restrict__ dinv,
                                                      const int* __restrict__ off,
                                                      const int* __restrict__ es,
                                                      const float* __restrict__ bias,
                                                      const float* __restrict__ a_ptr,
                                                      void* __restrict__ outv, int n) {
    constexpr int TPN = F / 8;                 // threads per node (8 bf16 = 16B each)
    int node = blockIdx.x * (THREADS / TPN) + (int)threadIdx.x / TPN;
    int l8   = (int)threadIdx.x % TPN;
    if (node >= n) return;
    const int fbase = l8 * 8;

    float acc[8];
    {   // self term (H already pre-scaled by dinv[node])
        uint4 v = *reinterpret_cast<const uint4*>(H + (size_t)node * F + fbase);
        acc[0] = bflo(v.x); acc[1] = bfhi(v.x);
        acc[2] = bflo(v.y); acc[3] = bfhi(v.y);
        acc[4] = bflo(v.z); acc[5] = bfhi(v.z);
        acc[6] = bflo(v.w); acc[7] = bfhi(v.w);
    }

    int j = off[node], j1 = off[node + 1];
    for (; j + 1 < j1; j += 2) {
        int s0 = es[j], s1 = es[j + 1];
        uint4 v0 = *reinterpret_cast<const uint4*>(H + (size_t)s0 * F + fbase);
        uint4 v1 = *reinterpret_cast<const uint4*>(H + (size_t)s1 * F + fbase);
        acc[0] += bflo(v0.x) + bflo(v1.x);
        acc[1] += bfhi(v0.x) + bfhi(v1.x);
        acc[2] += bflo(v0.y) + bflo(v1.y);
        acc[3] += bfhi(v0.y) + bfhi(v1.y);
        acc[4] += bflo(v0.z) + bflo(v1.z);
        acc[5] += bfhi(v0.z) + bfhi(v1.z);
        acc[6] += bflo(v0.w) + bflo(v1.w);
        acc[7] += bfhi(v0.w) + bfhi(v1.w);
    }
    if (j < j1) {
        int s0 = es[j];
        uint4 v0 = *reinterpret_cast<const uint4*>(H + (size_t)s0 * F + fbase);
        acc[0] += bflo(v0.x); acc[1] += bfhi(v0.x);
        acc[2] += bflo(v0.y); acc[3] += bfhi(v0.y);
        acc[4] += bflo(v0.z); acc[5] += bfhi(v0.z);
        acc[6] += bflo(v0.w); acc[7] += bfhi(v0.w);
    }

    float di = dinv[node];
    float a  = *a_ptr;
    float4 b0 = *reinterpret_cast<const float4*>(bias + fbase);
    float4 b1 = *reinterpret_cast<const float4*>(bias + fbase + 4);
    float bb[8] = {b0.x, b0.y, b0.z, b0.w, b1.x, b1.y, b1.z, b1.w};
    float o[8];
#pragma unroll
    for (int k = 0; k < 8; ++k) {
        float v = acc[k] * di + bb[k];
        o[k] = v >= 0.f ? v : a * v;
    }

    if constexpr (OUTBF) {
        uint4 w;
        w.x = f2bf(o[0]) | (f2bf(o[1]) << 16);
        w.y = f2bf(o[2]) | (f2bf(o[3]) << 16);
        w.z = f2bf(o[4]) | (f2bf(o[5]) << 16);
        w.w = f2bf(o[6]) | (f2bf(o[7]) << 16);
        *reinterpret_cast<uint4*>((bf16_t*)outv + (size_t)node * F + fbase) = w;
    } else {
        float* op = (float*)outv + (size_t)node * F + fbase;
        *reinterpret_cast<float4*>(op)     = make_float4(o[0], o[1], o[2], o[3]);
        *reinterpret_cast<float4*>(op + 4) = make_float4(o[4], o[5], o[6], o[7]);
    }
}

extern "C" void kernel_launch(void* const* d_in, const int* in_sizes, int n_in,
                              void* d_out, int out_size, void* d_ws, size_t ws_size,
                              hipStream_t stream) {
    const float* x   = (const float*)d_in[0];
    const int*   ei  = (const int*)d_in[1];
    const float* W1  = (const float*)d_in[2];
    const float* b1  = (const float*)d_in[3];
    const float* W2  = (const float*)d_in[4];
    const float* b2  = (const float*)d_in[5];
    const float* a   = (const float*)d_in[6];

    const int IN  = 128;
    const int HID = 128;
    const int OUT = 64;
    const int n = in_sizes[0] / IN;       // 100000
    const int e = in_sizes[1] / 2;        // 1600000
    const int* src = ei;
    const int* dst = ei + e;

    auto align = [](size_t v) { return (v + 255) / 256 * 256; };
    char* ws = (char*)d_ws;
    size_t o = 0;
    int*    deg    = (int*)(ws + o);    o += align((size_t)n * 4);
    float*  dinv   = (float*)(ws + o);  o += align((size_t)n * 4);
    int*    off    = (int*)(ws + o);    o += align(((size_t)n + 1) * 4);
    int*    cursor = (int*)(ws + o);    o += align((size_t)n * 4);
    int*    bsum   = (int*)(ws + o);    o += align((size_t)4096 * 4);
    int*    es     = (int*)(ws + o);    o += align((size_t)e * 4);
    bf16_t* h1     = (bf16_t*)(ws + o); o += align((size_t)n * HID * 2);
    bf16_t* h2     = (bf16_t*)(ws + o); o += align((size_t)n * HID * 2);
    bf16_t* g      = (bf16_t*)(ws + o); o += align((size_t)n * OUT * 2);

    float* out = (float*)d_out;

    int gbN = (n + THREADS - 1) / THREADS;
    int gbE = (e + THREADS - 1) / THREADS;
    int nb  = (n + SCAN_CHUNK - 1) / SCAN_CHUNK;

    // ---- CSR build + dinv ----
    zero_int_kernel<<<gbN, THREADS, 0, stream>>>(deg, n);
    count_deg_kernel<<<gbE, THREADS, 0, stream>>>(dst, deg, e);
    make_dinv_kernel<<<gbN, THREADS, 0, stream>>>(deg, dinv, n);
    scan_phaseA_kernel<<<nb, THREADS, 0, stream>>>(deg, bsum, n);
    scan_phaseB_kernel<<<1, THREADS, 0, stream>>>(bsum, nb);
    scan_phaseC_kernel<<<nb, THREADS, 0, stream>>>(deg, bsum, off, cursor, n);
    scatter_edges_kernel<<<gbE, THREADS, 0, stream>>>(src, dst, cursor, es, e);

    // ---- layer 1 ----
    {
        constexpr int ROWS = (THREADS / (128 / 4)) * 8;  // 64 rows/block
        int gb = (n + ROWS - 1) / ROWS;
        gemm_kernel<128, false><<<gb, THREADS, 0, stream>>>(x, W1, dinv, h1, n);
    }
    {
        constexpr int NPB = THREADS / (128 / 8);   // 16 nodes/block
        int gb = (n + NPB - 1) / NPB;
        agg_kernel<128, true><<<gb, THREADS, 0, stream>>>(h1, dinv, off, es, b1, a, h2, n);
    }

    // ---- layer 2 ----
    {
        constexpr int ROWS = (THREADS / (64 / 4)) * 8;   // 128 rows/block
        int gb = (n + ROWS - 1) / ROWS;
        gemm_kernel<64, true><<<gb, THREADS, 0, stream>>>(h2, W2, dinv, g, n);
    }
    {
        constexpr int NPB = THREADS / (64 / 8);    // 32 nodes/block
        int gb = (n + NPB - 1) / NPB;
        agg_kernel<64, false><<<gb, THREADS, 0, stream>>>(g, dinv, off, es, b2, a, out, n);
    }

    (void)ws_size; (void)n_in; (void)out_size;
}